// Round 3
// baseline (142.141 us; speedup 1.0000x reference)
//
#include <hip/hip_runtime.h>
#include <math.h>

#define N1 1024
#define DPROJ 1024
#define M_NODES 4368
#define N2 (N1 + M_NODES)      // 5392
#define N2P 5504               // padded to 43*128 for the GEMM
#define L_LEAVES 4096
#define INV_T (1.0f / 0.07f)

typedef __bf16 bf16;
typedef __bf16 bf16x4v __attribute__((ext_vector_type(4)));
typedef __bf16 bf16x8 __attribute__((ext_vector_type(8)));
typedef float f32x4 __attribute__((ext_vector_type(4)));

// ---------------------------------------------------------------------------
// Kernel A: fused normalize + bf16 cast. kn[row] = row/max(||row||,1e-12);
// rows >= N2 zero-filled (GEMM padding).
// ---------------------------------------------------------------------------
__global__ __launch_bounds__(256) void normalize_kernel(
    const float* __restrict__ q, const float* __restrict__ vc,
    bf16* __restrict__ kn) {
  const int row = blockIdx.x;
  bf16x4v* dst = (bf16x4v*)(kn + (size_t)row * DPROJ);
  if (row >= N2) {
    bf16x4v z = {(bf16)0.f, (bf16)0.f, (bf16)0.f, (bf16)0.f};
    dst[threadIdx.x] = z;
    return;
  }
  const float* src = (row < N1) ? q + (size_t)row * DPROJ
                                : vc + (size_t)(row - N1) * DPROJ;
  float4 v = ((const float4*)src)[threadIdx.x];
  float s = v.x * v.x + v.y * v.y + v.z * v.z + v.w * v.w;
  for (int off = 32; off > 0; off >>= 1) s += __shfl_down(s, off);
  __shared__ float wsum[4];
  const int lane = threadIdx.x & 63, wid = threadIdx.x >> 6;
  if (lane == 0) wsum[wid] = s;
  __syncthreads();
  const float tot = wsum[0] + wsum[1] + wsum[2] + wsum[3];
  const float inv = 1.0f / fmaxf(sqrtf(tot), 1e-12f);
  bf16x4v o = {(bf16)(v.x * inv), (bf16)(v.y * inv), (bf16)(v.z * inv),
               (bf16)(v.w * inv)};
  dst[threadIdx.x] = o;
}

// ---------------------------------------------------------------------------
// Kernel B: label histogram, indexed like node ids:
//   hist[0..4095]=leaf counts, hist[4096+c2], hist[4352+c1].
// ---------------------------------------------------------------------------
__global__ __launch_bounds__(256) void hist_kernel(
    const int* __restrict__ labels, int* __restrict__ hist) {
  const int t = blockIdx.x * 256 + threadIdx.x;
  if (t < N1) {
    const int lab = labels[t];
    atomicAdd(&hist[lab], 1);
    atomicAdd(&hist[L_LEAVES + (lab >> 4)], 1);
    atomicAdd(&hist[L_LEAVES + 256 + (lab >> 8)], 1);
  }
}

// ---------------------------------------------------------------------------
// Kernel C: fused GEMM + loss partials.
// logits = (KN[0:1024].KN^T)*INV_T, never materialized: the epilogue
// classifies each column vs the row's label analytically and reduces
// {pos-logit-sum, neg-exp-sum} x 3 slots per row into `partials` (atomics).
// GEMM: 128x128 tile, BK=32, 2x2 waves, double-buffered LDS, 2-phase
// pipeline (counted vmcnt(4), raw s_barrier), XOR-swizzled LDS k-slots
// (pre-swizzled global source + swizzled read: rule both-sides-or-neither).
// ---------------------------------------------------------------------------
#define BM 128
#define BN 128
#define BK 32
#define NT (DPROJ / BK)

__device__ __forceinline__ void gload16(const bf16* g, bf16* l) {
  __builtin_amdgcn_global_load_lds(
      (const __attribute__((address_space(1))) void*)g,
      (__attribute__((address_space(3))) void*)l, 16, 0, 0);
}

__global__ __launch_bounds__(256) void gemm_loss_kernel(
    const bf16* __restrict__ kn, const int* __restrict__ labels,
    float* __restrict__ partials) {
  __shared__ bf16 As[2][BM][BK];   // 2 x 8 KB
  __shared__ bf16 Bs[2][BN][BK];
  __shared__ int lab_s[N1];        // 4 KB
  const int j0 = blockIdx.x * BN;
  const int i0 = blockIdx.y * BM;
  const int t = threadIdx.x;
  const int lane = t & 63, w = t >> 6;
  const int wm = w >> 1, wn = w & 1;   // wave grid 2x2, each 64x64

  ((int4*)lab_s)[t] = ((const int4*)labels)[t];

  f32x4 acc[4][4] = {};

  // Staging: wave w stages 16-row chunks {w, w+4}. lane -> (row=lane>>2,
  // 16B slot=lane&3). Global k-slot pre-swizzled by row&3 so the linear
  // LDS write lands the swizzled layout.
  const int rik = lane >> 2;
  const int kswz = ((lane & 3) ^ (rik & 3)) * 8;
  const bf16* gA0 = kn + (size_t)(i0 + w * 16 + rik) * DPROJ + kswz;
  const bf16* gA1 = gA0 + (size_t)64 * DPROJ;
  const bf16* gB0 = kn + (size_t)(j0 + w * 16 + rik) * DPROJ + kswz;
  const bf16* gB1 = gB0 + (size_t)64 * DPROJ;

  // Fragment read: row = ..+ (lane&15) (row&3 == lane&3), logical k-slot
  // = lane>>4  ->  LDS slot = (lane>>4) ^ (lane&3). Conflict-free.
  const int ar = wm * 64 + (lane & 15);
  const int br = wn * 64 + (lane & 15);
  const int kf = (((lane >> 4) ^ (lane & 3)) * 8);

  // prologue: stage tile 0 into buf 0
  gload16(gA0, &As[0][w * 16][0]);
  gload16(gA1, &As[0][w * 16 + 64][0]);
  gload16(gB0, &Bs[0][w * 16][0]);
  gload16(gB1, &Bs[0][w * 16 + 64][0]);
  __syncthreads();   // full drain once: labels + tile0 visible

  for (int it = 0; it < NT; ++it) {
    const int cur = it & 1;
    if (it + 1 < NT) {
      const int k0 = (it + 1) * BK;
      gload16(gA0 + k0, &As[cur ^ 1][w * 16][0]);
      gload16(gA1 + k0, &As[cur ^ 1][w * 16 + 64][0]);
      gload16(gB0 + k0, &Bs[cur ^ 1][w * 16][0]);
      gload16(gB1 + k0, &Bs[cur ^ 1][w * 16 + 64][0]);
      asm volatile("s_waitcnt vmcnt(4)" ::: "memory");  // current tile done
    } else {
      asm volatile("s_waitcnt vmcnt(0)" ::: "memory");
    }
    __builtin_amdgcn_s_barrier();
    __builtin_amdgcn_sched_barrier(0);

    bf16x8 a[4], b[4];
#pragma unroll
    for (int m = 0; m < 4; ++m)
      a[m] = *(const bf16x8*)&As[cur][ar + m * 16][kf];
#pragma unroll
    for (int n = 0; n < 4; ++n)
      b[n] = *(const bf16x8*)&Bs[cur][br + n * 16][kf];
#pragma unroll
    for (int m = 0; m < 4; ++m)
#pragma unroll
      for (int n = 0; n < 4; ++n)
        acc[m][n] = __builtin_amdgcn_mfma_f32_16x16x32_bf16(
            a[m], b[n], acc[m][n], 0, 0, 0);
    __builtin_amdgcn_s_barrier();
  }

  // Fused epilogue. C/D layout: col=lane&15, row=(lane>>4)*4+j [m89].
  const int g = lane >> 4;
  const int p = lane & 15;
#pragma unroll
  for (int m = 0; m < 4; ++m) {
#pragma unroll
    for (int j = 0; j < 4; ++j) {
      const int gr = i0 + wm * 64 + m * 16 + g * 4 + j;
      const int lab = lab_s[gr];
      const int a2 = lab >> 4, a1 = lab >> 8;
      float ps0 = 0, ps1 = 0, ps2 = 0, ns0 = 0, ns1 = 0, ns2 = 0;
#pragma unroll
      for (int n = 0; n < 4; ++n) {
        const int gc = j0 + wn * 64 + n * 16 + p;
        if (gc < N2) {
          const int nid = (gc < N1) ? lab_s[gc] : (gc - N1);
          const bool isLeaf = nid < L_LEAVES;
          const bool isD2 = (nid >= L_LEAVES) && (nid < L_LEAVES + 256);
          const bool eq = (nid == lab);
          const bool inS2 =
              (nid == L_LEAVES + a2) || (isLeaf && ((nid >> 4) == a2));
          const bool inS1 = (nid == L_LEAVES + 256 + a1) ||
                            (isD2 && (((nid - L_LEAVES) >> 4) == a1)) ||
                            (isLeaf && ((nid >> 8) == a1));
          const float v = acc[m][n][j] * INV_T;
          const float e = __expf(v);
          if (eq) ps2 += v; else ns2 += e;
          if (inS2) { if (!eq) ps1 += v; } else ns1 += e;
          if (inS1) { if (!inS2) ps0 += v; } else ns0 += e;
        }
      }
#pragma unroll
      for (int msk = 1; msk < 16; msk <<= 1) {
        ps0 += __shfl_xor(ps0, msk);
        ps1 += __shfl_xor(ps1, msk);
        ps2 += __shfl_xor(ps2, msk);
        ns0 += __shfl_xor(ns0, msk);
        ns1 += __shfl_xor(ns1, msk);
        ns2 += __shfl_xor(ns2, msk);
      }
      if (p == 0) {
        float* dst = partials + (size_t)gr * 6;
        atomicAdd(dst + 0, ps0);
        atomicAdd(dst + 1, ps1);
        atomicAdd(dst + 2, ps2);
        atomicAdd(dst + 3, ns0);
        atomicAdd(dst + 4, ns1);
        atomicAdd(dst + 5, ns2);
      }
    }
  }
}

// ---------------------------------------------------------------------------
// Kernel D: finalize. Counts are analytic from the histogram:
//  |eq| = hist[lab]+1; |S2| = hist2+17; |S1| = hist1+273. Masked (non-neg)
//  entries contribute exp(0)=1 each -> +|set| inside the logsumexp.
// ---------------------------------------------------------------------------
__global__ __launch_bounds__(256) void finalize_kernel(
    const float* __restrict__ partials, const int* __restrict__ labels,
    const int* __restrict__ hist, const float* __restrict__ depth,
    float* __restrict__ out) {
  const int row = blockIdx.x * 256 + threadIdx.x;
  const int lab = labels[row];
  const int a2 = lab >> 4, a1 = lab >> 8;
  const int cEq = hist[lab] + 1;
  const int cS2 = hist[L_LEAVES + a2] + 17;
  const int cS1 = hist[L_LEAVES + 256 + a1] + 273;
  const float* pp = partials + (size_t)row * 6;
  const float ps0 = pp[0], ps1 = pp[1], ps2 = pp[2];
  const float ns0 = pp[3], ns1 = pp[4], ns2 = pp[5];
  float ce = 0.f;
  {
    float pl = ps2 / fmaxf((float)cEq, 1e-6f);
    ce += logf(ns2 + (float)cEq + __expf(pl)) - pl;
  }
  {
    float pl = ps1 / fmaxf((float)(cS2 - cEq), 1e-6f);
    ce += logf(ns1 + (float)cS2 + __expf(pl)) - pl;
  }
  {
    float pl = ps0 / fmaxf((float)(cS1 - cS2), 1e-6f);
    ce += logf(ns0 + (float)cS1 + __expf(pl)) - pl;
  }
  float contrib = ce / depth[lab] * (3.0f / (float)N1);
  for (int off = 32; off > 0; off >>= 1) contrib += __shfl_down(contrib, off);
  __shared__ float wsum[4];
  const int lane = threadIdx.x & 63, wid = threadIdx.x >> 6;
  if (lane == 0) wsum[wid] = contrib;
  __syncthreads();
  if (threadIdx.x == 0) {
    const float tot = wsum[0] + wsum[1] + wsum[2] + wsum[3];
    atomicAdd(&out[0], tot);
    atomicAdd(&out[1], tot);
  }
}

// ---------------------------------------------------------------------------
extern "C" void kernel_launch(void* const* d_in, const int* in_sizes, int n_in,
                              void* d_out, int out_size, void* d_ws,
                              size_t ws_size, hipStream_t stream) {
  const float* q = (const float*)d_in[0];
  const float* vc = (const float*)d_in[1];
  const int* labels = (const int*)d_in[2];
  const float* depth = (const float*)d_in[6];
  float* out = (float*)d_out;

  bf16* kn = (bf16*)d_ws;  // N2P*DPROJ bf16 = 11.27 MB
  float* partials = (float*)((char*)d_ws + (size_t)N2P * DPROJ * sizeof(bf16));
  int* hist = (int*)((char*)partials + (size_t)N1 * 6 * sizeof(float));

  hipMemsetAsync(partials, 0,
                 (size_t)N1 * 6 * sizeof(float) + (size_t)M_NODES * sizeof(int),
                 stream);
  hipMemsetAsync(d_out, 0, 2 * sizeof(float), stream);

  normalize_kernel<<<N2P, 256, 0, stream>>>(q, vc, kn);
  hist_kernel<<<4, 256, 0, stream>>>(labels, hist);

  dim3 grid(N2P / BN, N1 / BM);
  gemm_loss_kernel<<<grid, 256, 0, stream>>>(kn, labels, partials);

  finalize_kernel<<<4, 256, 0, stream>>>(partials, labels, hist, depth, out);
}

// Round 4
// 117.955 us; speedup vs baseline: 1.2050x; 1.2050x over previous
//
#include <hip/hip_runtime.h>
#include <math.h>

#define N1 1024
#define DPROJ 1024
#define M_NODES 4368
#define N2 (N1 + M_NODES)      // 5392
#define N2P 5504               // padded to 43*128 for the GEMM
#define L_LEAVES 4096
#define INV_T (1.0f / 0.07f)

typedef __bf16 bf16;
typedef __bf16 bf16x4v __attribute__((ext_vector_type(4)));
typedef __bf16 bf16x8 __attribute__((ext_vector_type(8)));
typedef float f32x4 __attribute__((ext_vector_type(4)));

// ---------------------------------------------------------------------------
// Kernel A: fused normalize + bf16 cast. kn[row] = row/max(||row||,1e-12);
// rows >= N2 zero-filled (GEMM padding).
// ---------------------------------------------------------------------------
__global__ __launch_bounds__(256) void normalize_kernel(
    const float* __restrict__ q, const float* __restrict__ vc,
    bf16* __restrict__ kn) {
  const int row = blockIdx.x;
  bf16x4v* dst = (bf16x4v*)(kn + (size_t)row * DPROJ);
  if (row >= N2) {
    bf16x4v z = {(bf16)0.f, (bf16)0.f, (bf16)0.f, (bf16)0.f};
    dst[threadIdx.x] = z;
    return;
  }
  const float* src = (row < N1) ? q + (size_t)row * DPROJ
                                : vc + (size_t)(row - N1) * DPROJ;
  float4 v = ((const float4*)src)[threadIdx.x];
  float s = v.x * v.x + v.y * v.y + v.z * v.z + v.w * v.w;
  for (int off = 32; off > 0; off >>= 1) s += __shfl_down(s, off);
  __shared__ float wsum[4];
  const int lane = threadIdx.x & 63, wid = threadIdx.x >> 6;
  if (lane == 0) wsum[wid] = s;
  __syncthreads();
  const float tot = wsum[0] + wsum[1] + wsum[2] + wsum[3];
  const float inv = 1.0f / fmaxf(sqrtf(tot), 1e-12f);
  bf16x4v o = {(bf16)(v.x * inv), (bf16)(v.y * inv), (bf16)(v.z * inv),
               (bf16)(v.w * inv)};
  dst[threadIdx.x] = o;
}

// ---------------------------------------------------------------------------
// Kernel B: label histogram in node-id space.
// ---------------------------------------------------------------------------
__global__ __launch_bounds__(256) void hist_kernel(
    const int* __restrict__ labels, int* __restrict__ hist) {
  const int t = blockIdx.x * 256 + threadIdx.x;
  if (t < N1) {
    const int lab = labels[t];
    atomicAdd(&hist[lab], 1);
    atomicAdd(&hist[L_LEAVES + (lab >> 4)], 1);
    atomicAdd(&hist[L_LEAVES + 256 + (lab >> 8)], 1);
  }
}

// ---------------------------------------------------------------------------
// Kernel C: fused GEMM + loss partials.
// 64x128 tile (BM=64, BN=128), BK=32, 4 waves as 2x2 (wave tile 32x64),
// single-buffered LDS with the R2-proven vmcnt(0)+syncthreads loop
// (2-phase counted-vmcnt graft measured 2.3x WORSE in R3 — compiler
// re-drains vmcnt before ds_read; see R3 post-mortem). Grid 43x16=688
// blocks -> all resident, ~11 waves/CU for TLP latency hiding.
// Epilogue classifies each column vs the row's label analytically and
// atomically accumulates {pos-logit-sum, neg-exp-sum} x 3 slots per row.
// ---------------------------------------------------------------------------
#define BM 64
#define BN 128
#define BK 32
#define NT (DPROJ / BK)

__device__ __forceinline__ void gload16(const bf16* g, bf16* l) {
  __builtin_amdgcn_global_load_lds(
      (const __attribute__((address_space(1))) void*)g,
      (__attribute__((address_space(3))) void*)l, 16, 0, 0);
}

__global__ __launch_bounds__(256, 4) void gemm_loss_kernel(
    const bf16* __restrict__ kn, const int* __restrict__ labels,
    float* __restrict__ partials) {
  __shared__ bf16 As[BM][BK];   // 4 KB
  __shared__ bf16 Bs[BN][BK];   // 8 KB
  __shared__ int lab_s[N1];     // 4 KB
  const int j0 = blockIdx.x * BN;
  const int i0 = blockIdx.y * BM;
  const int t = threadIdx.x;
  const int lane = t & 63, w = t >> 6;
  const int wm = w >> 1, wn = w & 1;   // wave grid 2x2, wave tile 32x64

  ((int4*)lab_s)[t] = ((const int4*)labels)[t];

  f32x4 acc[2][4] = {};

  // Staging: wave w stages A rows [16w,16w+16) and B rows {16w.., 16w+64..}.
  // lane -> (row=lane>>2, 16B k-slot=lane&3); LDS dest linear (HW rule).
  const int rik = lane >> 2;
  const int kk = (lane & 3) * 8;
  const bf16* gA = kn + (size_t)(i0 + w * 16 + rik) * DPROJ + kk;
  const bf16* gB0 = kn + (size_t)(j0 + w * 16 + rik) * DPROJ + kk;
  const bf16* gB1 = gB0 + (size_t)64 * DPROJ;
  bf16* lA = &As[w * 16][0];
  bf16* lB0 = &Bs[w * 16][0];
  bf16* lB1 = &Bs[w * 16 + 64][0];

  // Fragment reads (64 B row stride -> benign bank pattern, R2-measured)
  const int ar = wm * 32 + (lane & 15);
  const int br = wn * 64 + (lane & 15);
  const int kf = (lane >> 4) * 8;

  for (int k0 = 0; k0 < DPROJ; k0 += BK) {
    gload16(gA + k0, lA);
    gload16(gB0 + k0, lB0);
    gload16(gB1 + k0, lB1);
    asm volatile("s_waitcnt vmcnt(0)" ::: "memory");
    __syncthreads();

    bf16x8 a[2], b[4];
#pragma unroll
    for (int m = 0; m < 2; ++m)
      a[m] = *(const bf16x8*)&As[ar + m * 16][kf];
#pragma unroll
    for (int n = 0; n < 4; ++n)
      b[n] = *(const bf16x8*)&Bs[br + n * 16][kf];
#pragma unroll
    for (int m = 0; m < 2; ++m)
#pragma unroll
      for (int n = 0; n < 4; ++n)
        acc[m][n] = __builtin_amdgcn_mfma_f32_16x16x32_bf16(
            a[m], b[n], acc[m][n], 0, 0, 0);
    __syncthreads();
  }

  // Fused epilogue. C/D layout: col=lane&15, row=(lane>>4)*4+j [m89].
  const int g = lane >> 4;
  const int p = lane & 15;
#pragma unroll
  for (int m = 0; m < 2; ++m) {
#pragma unroll
    for (int j = 0; j < 4; ++j) {
      const int gr = i0 + wm * 32 + m * 16 + g * 4 + j;
      const int lab = lab_s[gr];
      const int a2 = lab >> 4, a1 = lab >> 8;
      float ps0 = 0, ps1 = 0, ps2 = 0, ns0 = 0, ns1 = 0, ns2 = 0;
#pragma unroll
      for (int n = 0; n < 4; ++n) {
        const int gc = j0 + wn * 64 + n * 16 + p;
        if (gc < N2) {
          const int nid = (gc < N1) ? lab_s[gc] : (gc - N1);
          const bool isLeaf = nid < L_LEAVES;
          const bool isD2 = (nid >= L_LEAVES) && (nid < L_LEAVES + 256);
          const bool eq = (nid == lab);
          const bool inS2 =
              (nid == L_LEAVES + a2) || (isLeaf && ((nid >> 4) == a2));
          const bool inS1 = (nid == L_LEAVES + 256 + a1) ||
                            (isD2 && (((nid - L_LEAVES) >> 4) == a1)) ||
                            (isLeaf && ((nid >> 8) == a1));
          const float v = acc[m][n][j] * INV_T;
          const float e = __expf(v);
          if (eq) ps2 += v; else ns2 += e;
          if (inS2) { if (!eq) ps1 += v; } else ns1 += e;
          if (inS1) { if (!inS2) ps0 += v; } else ns0 += e;
        }
      }
#pragma unroll
      for (int msk = 1; msk < 16; msk <<= 1) {
        ps0 += __shfl_xor(ps0, msk);
        ps1 += __shfl_xor(ps1, msk);
        ps2 += __shfl_xor(ps2, msk);
        ns0 += __shfl_xor(ns0, msk);
        ns1 += __shfl_xor(ns1, msk);
        ns2 += __shfl_xor(ns2, msk);
      }
      if (p == 0) {
        float* dst = partials + (size_t)gr * 6;
        atomicAdd(dst + 0, ps0);
        atomicAdd(dst + 1, ps1);
        atomicAdd(dst + 2, ps2);
        atomicAdd(dst + 3, ns0);
        atomicAdd(dst + 4, ns1);
        atomicAdd(dst + 5, ns2);
      }
    }
  }
}

// ---------------------------------------------------------------------------
// Kernel D: finalize with analytic counts from the histogram.
//  |eq| = hist[lab]+1; |S2| = hist2+17; |S1| = hist1+273. Masked (non-neg)
//  entries contribute exp(0)=1 each -> +|set| inside the logsumexp.
// ---------------------------------------------------------------------------
__global__ __launch_bounds__(256) void finalize_kernel(
    const float* __restrict__ partials, const int* __restrict__ labels,
    const int* __restrict__ hist, const float* __restrict__ depth,
    float* __restrict__ out) {
  const int row = blockIdx.x * 256 + threadIdx.x;
  const int lab = labels[row];
  const int a2 = lab >> 4, a1 = lab >> 8;
  const int cEq = hist[lab] + 1;
  const int cS2 = hist[L_LEAVES + a2] + 17;
  const int cS1 = hist[L_LEAVES + 256 + a1] + 273;
  const float* pp = partials + (size_t)row * 6;
  const float ps0 = pp[0], ps1 = pp[1], ps2 = pp[2];
  const float ns0 = pp[3], ns1 = pp[4], ns2 = pp[5];
  float ce = 0.f;
  {
    float pl = ps2 / fmaxf((float)cEq, 1e-6f);
    ce += logf(ns2 + (float)cEq + __expf(pl)) - pl;
  }
  {
    float pl = ps1 / fmaxf((float)(cS2 - cEq), 1e-6f);
    ce += logf(ns1 + (float)cS2 + __expf(pl)) - pl;
  }
  {
    float pl = ps0 / fmaxf((float)(cS1 - cS2), 1e-6f);
    ce += logf(ns0 + (float)cS1 + __expf(pl)) - pl;
  }
  float contrib = ce / depth[lab] * (3.0f / (float)N1);
  for (int off = 32; off > 0; off >>= 1) contrib += __shfl_down(contrib, off);
  __shared__ float wsum[4];
  const int lane = threadIdx.x & 63, wid = threadIdx.x >> 6;
  if (lane == 0) wsum[wid] = contrib;
  __syncthreads();
  if (threadIdx.x == 0) {
    const float tot = wsum[0] + wsum[1] + wsum[2] + wsum[3];
    atomicAdd(&out[0], tot);
    atomicAdd(&out[1], tot);
  }
}

// ---------------------------------------------------------------------------
extern "C" void kernel_launch(void* const* d_in, const int* in_sizes, int n_in,
                              void* d_out, int out_size, void* d_ws,
                              size_t ws_size, hipStream_t stream) {
  const float* q = (const float*)d_in[0];
  const float* vc = (const float*)d_in[1];
  const int* labels = (const int*)d_in[2];
  const float* depth = (const float*)d_in[6];
  float* out = (float*)d_out;

  bf16* kn = (bf16*)d_ws;  // N2P*DPROJ bf16 = 11.27 MB
  float* partials = (float*)((char*)d_ws + (size_t)N2P * DPROJ * sizeof(bf16));
  int* hist = (int*)((char*)partials + (size_t)N1 * 6 * sizeof(float));

  hipMemsetAsync(partials, 0,
                 (size_t)N1 * 6 * sizeof(float) + (size_t)M_NODES * sizeof(int),
                 stream);
  hipMemsetAsync(d_out, 0, 2 * sizeof(float), stream);

  normalize_kernel<<<N2P, 256, 0, stream>>>(q, vc, kn);
  hist_kernel<<<4, 256, 0, stream>>>(labels, hist);

  dim3 grid(N2P / BN, N1 / BM);
  gemm_loss_kernel<<<grid, 256, 0, stream>>>(kn, labels, partials);

  finalize_kernel<<<4, 256, 0, stream>>>(partials, labels, hist, depth, out);
}

// Round 5
// 66.428 us; speedup vs baseline: 2.1398x; 1.7757x over previous
//
#include <hip/hip_runtime.h>
#include <math.h>

#define N1 1024
#define DPROJ 1024
#define M_NODES 4368
#define N2 (N1 + M_NODES)      // 5392
#define N2P 5504               // padded to 43*128 for the GEMM
#define L_LEAVES 4096
#define INV_T (1.0f / 0.07f)
#define NBX 43                 // N2P / BN

typedef __bf16 bf16;
typedef __bf16 bf16x4v __attribute__((ext_vector_type(4)));
typedef __bf16 bf16x8 __attribute__((ext_vector_type(8)));
typedef float f32x4 __attribute__((ext_vector_type(4)));

// ---------------------------------------------------------------------------
// Kernel A: fused normalize + bf16 cast. kn[row] = row/max(||row||,1e-12);
// rows >= N2 zero-filled (GEMM padding).
// ---------------------------------------------------------------------------
__global__ __launch_bounds__(256) void normalize_kernel(
    const float* __restrict__ q, const float* __restrict__ vc,
    bf16* __restrict__ kn) {
  const int row = blockIdx.x;
  bf16x4v* dst = (bf16x4v*)(kn + (size_t)row * DPROJ);
  if (row >= N2) {
    bf16x4v z = {(bf16)0.f, (bf16)0.f, (bf16)0.f, (bf16)0.f};
    dst[threadIdx.x] = z;
    return;
  }
  const float* src = (row < N1) ? q + (size_t)row * DPROJ
                                : vc + (size_t)(row - N1) * DPROJ;
  float4 v = ((const float4*)src)[threadIdx.x];
  float s = v.x * v.x + v.y * v.y + v.z * v.z + v.w * v.w;
  for (int off = 32; off > 0; off >>= 1) s += __shfl_down(s, off);
  __shared__ float wsum[4];
  const int lane = threadIdx.x & 63, wid = threadIdx.x >> 6;
  if (lane == 0) wsum[wid] = s;
  __syncthreads();
  const float tot = wsum[0] + wsum[1] + wsum[2] + wsum[3];
  const float inv = 1.0f / fmaxf(sqrtf(tot), 1e-12f);
  bf16x4v o = {(bf16)(v.x * inv), (bf16)(v.y * inv), (bf16)(v.z * inv),
               (bf16)(v.w * inv)};
  dst[threadIdx.x] = o;
}

// ---------------------------------------------------------------------------
// Kernel B: label histogram in node-id space.
// ---------------------------------------------------------------------------
__global__ __launch_bounds__(256) void hist_kernel(
    const int* __restrict__ labels, int* __restrict__ hist) {
  const int t = blockIdx.x * 256 + threadIdx.x;
  if (t < N1) {
    const int lab = labels[t];
    atomicAdd(&hist[lab], 1);
    atomicAdd(&hist[L_LEAVES + (lab >> 4)], 1);
    atomicAdd(&hist[L_LEAVES + 256 + (lab >> 8)], 1);
  }
}

// ---------------------------------------------------------------------------
// Kernel C: fused GEMM + loss partials. Geometry identical to R4 (64x128
// tile, BK=32, 2x2 waves of 32x64, single-buffered vmcnt(0)+syncthreads
// loop, 688 blocks). ONLY change vs R4: the epilogue reduction goes
// through LDS (blk_part[row][wn][6], disjoint slots -> zero atomics) and
// one cooperative plain store per block into partials[row][bx][6].
// R4 post-mortem: 264K contended global atomicAdds onto 384 cache lines
// cost ~50 us; this removes all of them.
// ---------------------------------------------------------------------------
#define BM 64
#define BN 128
#define BK 32
#define NT (DPROJ / BK)

__device__ __forceinline__ void gload16(const bf16* g, bf16* l) {
  __builtin_amdgcn_global_load_lds(
      (const __attribute__((address_space(1))) void*)g,
      (__attribute__((address_space(3))) void*)l, 16, 0, 0);
}

__global__ __launch_bounds__(256, 4) void gemm_loss_kernel(
    const bf16* __restrict__ kn, const int* __restrict__ labels,
    float* __restrict__ partials) {
  __shared__ bf16 As[BM][BK];            // 4 KB
  __shared__ bf16 Bs[BN][BK];            // 8 KB
  __shared__ int lab_s[N1];              // 4 KB
  __shared__ float blk_part[BM][2][6];   // 3 KB
  const int bx = blockIdx.x;
  const int j0 = bx * BN;
  const int i0 = blockIdx.y * BM;
  const int t = threadIdx.x;
  const int lane = t & 63, w = t >> 6;
  const int wm = w >> 1, wn = w & 1;   // wave grid 2x2, wave tile 32x64

  ((int4*)lab_s)[t] = ((const int4*)labels)[t];

  f32x4 acc[2][4] = {};

  // Staging: wave w stages A rows [16w,16w+16) and B rows {16w.., 16w+64..}.
  const int rik = lane >> 2;
  const int kk = (lane & 3) * 8;
  const bf16* gA = kn + (size_t)(i0 + w * 16 + rik) * DPROJ + kk;
  const bf16* gB0 = kn + (size_t)(j0 + w * 16 + rik) * DPROJ + kk;
  const bf16* gB1 = gB0 + (size_t)64 * DPROJ;
  bf16* lA = &As[w * 16][0];
  bf16* lB0 = &Bs[w * 16][0];
  bf16* lB1 = &Bs[w * 16 + 64][0];

  const int ar = wm * 32 + (lane & 15);
  const int br = wn * 64 + (lane & 15);
  const int kf = (lane >> 4) * 8;

  for (int k0 = 0; k0 < DPROJ; k0 += BK) {
    gload16(gA + k0, lA);
    gload16(gB0 + k0, lB0);
    gload16(gB1 + k0, lB1);
    asm volatile("s_waitcnt vmcnt(0)" ::: "memory");
    __syncthreads();

    bf16x8 a[2], b[4];
#pragma unroll
    for (int m = 0; m < 2; ++m)
      a[m] = *(const bf16x8*)&As[ar + m * 16][kf];
#pragma unroll
    for (int n = 0; n < 4; ++n)
      b[n] = *(const bf16x8*)&Bs[br + n * 16][kf];
#pragma unroll
    for (int m = 0; m < 2; ++m)
#pragma unroll
      for (int n = 0; n < 4; ++n)
        acc[m][n] = __builtin_amdgcn_mfma_f32_16x16x32_bf16(
            a[m], b[n], acc[m][n], 0, 0, 0);
    __syncthreads();
  }

  // Fused epilogue. C/D layout: col=lane&15, row=(lane>>4)*4+j [m89].
  const int g = lane >> 4;
  const int p = lane & 15;
#pragma unroll
  for (int m = 0; m < 2; ++m) {
#pragma unroll
    for (int j = 0; j < 4; ++j) {
      const int rloc = wm * 32 + m * 16 + g * 4 + j;
      const int gr = i0 + rloc;
      const int lab = lab_s[gr];
      const int a2 = lab >> 4, a1 = lab >> 8;
      float ps0 = 0, ps1 = 0, ps2 = 0, ns0 = 0, ns1 = 0, ns2 = 0;
#pragma unroll
      for (int n = 0; n < 4; ++n) {
        const int gc = j0 + wn * 64 + n * 16 + p;
        if (gc < N2) {
          const int nid = (gc < N1) ? lab_s[gc] : (gc - N1);
          const bool isLeaf = nid < L_LEAVES;
          const bool isD2 = (nid >= L_LEAVES) && (nid < L_LEAVES + 256);
          const bool eq = (nid == lab);
          const bool inS2 =
              (nid == L_LEAVES + a2) || (isLeaf && ((nid >> 4) == a2));
          const bool inS1 = (nid == L_LEAVES + 256 + a1) ||
                            (isD2 && (((nid - L_LEAVES) >> 4) == a1)) ||
                            (isLeaf && ((nid >> 8) == a1));
          const float v = acc[m][n][j] * INV_T;
          const float e = __expf(v);
          if (eq) ps2 += v; else ns2 += e;
          if (inS2) { if (!eq) ps1 += v; } else ns1 += e;
          if (inS1) { if (!inS2) ps0 += v; } else ns0 += e;
        }
      }
#pragma unroll
      for (int msk = 1; msk < 16; msk <<= 1) {
        ps0 += __shfl_xor(ps0, msk);
        ps1 += __shfl_xor(ps1, msk);
        ps2 += __shfl_xor(ps2, msk);
        ns0 += __shfl_xor(ns0, msk);
        ns1 += __shfl_xor(ns1, msk);
        ns2 += __shfl_xor(ns2, msk);
      }
      if (p == 0) {
        float* d = &blk_part[rloc][wn][0];
        d[0] = ps0; d[1] = ps1; d[2] = ps2;
        d[3] = ns0; d[4] = ns1; d[5] = ns2;
      }
    }
  }
  __syncthreads();
  // One plain store per (row, slot): partials[gr][bx][k], k=0..5.
  for (int idx = t; idx < BM * 6; idx += 256) {
    const int r = idx / 6, k = idx % 6;
    const float val = blk_part[r][0][k] + blk_part[r][1][k];
    partials[((size_t)(i0 + r) * NBX + bx) * 6 + k] = val;
  }
}

// ---------------------------------------------------------------------------
// Kernel D: finalize. Sum the 43 per-block-column slices per row, then CE
// with analytic counts from the histogram:
//  |eq| = hist[lab]+1; |S2| = hist2+17; |S1| = hist1+273. Masked (non-neg)
//  entries contribute exp(0)=1 each -> +|set| inside the logsumexp.
// ---------------------------------------------------------------------------
__global__ __launch_bounds__(256) void finalize_kernel(
    const float* __restrict__ partials, const int* __restrict__ labels,
    const int* __restrict__ hist, const float* __restrict__ depth,
    float* __restrict__ out) {
  const int row = blockIdx.x * 256 + threadIdx.x;
  const int lab = labels[row];
  const int a2 = lab >> 4, a1 = lab >> 8;
  const int cEq = hist[lab] + 1;
  const int cS2 = hist[L_LEAVES + a2] + 17;
  const int cS1 = hist[L_LEAVES + 256 + a1] + 273;
  float ps0 = 0, ps1 = 0, ps2 = 0, ns0 = 0, ns1 = 0, ns2 = 0;
  const float* pp = partials + (size_t)row * NBX * 6;
  for (int b = 0; b < NBX; ++b) {
    ps0 += pp[b * 6 + 0];
    ps1 += pp[b * 6 + 1];
    ps2 += pp[b * 6 + 2];
    ns0 += pp[b * 6 + 3];
    ns1 += pp[b * 6 + 4];
    ns2 += pp[b * 6 + 5];
  }
  float ce = 0.f;
  {
    float pl = ps2 / fmaxf((float)cEq, 1e-6f);
    ce += logf(ns2 + (float)cEq + __expf(pl)) - pl;
  }
  {
    float pl = ps1 / fmaxf((float)(cS2 - cEq), 1e-6f);
    ce += logf(ns1 + (float)cS2 + __expf(pl)) - pl;
  }
  {
    float pl = ps0 / fmaxf((float)(cS1 - cS2), 1e-6f);
    ce += logf(ns0 + (float)cS1 + __expf(pl)) - pl;
  }
  float contrib = ce / depth[lab] * (3.0f / (float)N1);
  for (int off = 32; off > 0; off >>= 1) contrib += __shfl_down(contrib, off);
  __shared__ float wsum[4];
  const int lane = threadIdx.x & 63, wid = threadIdx.x >> 6;
  if (lane == 0) wsum[wid] = contrib;
  __syncthreads();
  if (threadIdx.x == 0) {
    const float tot = wsum[0] + wsum[1] + wsum[2] + wsum[3];
    atomicAdd(&out[0], tot);
    atomicAdd(&out[1], tot);
  }
}

// ---------------------------------------------------------------------------
extern "C" void kernel_launch(void* const* d_in, const int* in_sizes, int n_in,
                              void* d_out, int out_size, void* d_ws,
                              size_t ws_size, hipStream_t stream) {
  const float* q = (const float*)d_in[0];
  const float* vc = (const float*)d_in[1];
  const int* labels = (const int*)d_in[2];
  const float* depth = (const float*)d_in[6];
  float* out = (float*)d_out;

  bf16* kn = (bf16*)d_ws;  // N2P*DPROJ bf16 = 11.27 MB
  float* partials = (float*)((char*)d_ws + (size_t)N2P * DPROJ * sizeof(bf16));
  // partials: N1 * NBX * 6 floats (~1.06 MB), fully written -> no memset
  int* hist = (int*)((char*)partials + (size_t)N1 * NBX * 6 * sizeof(float));

  hipMemsetAsync(hist, 0, (size_t)M_NODES * sizeof(int), stream);
  hipMemsetAsync(d_out, 0, 2 * sizeof(float), stream);

  normalize_kernel<<<N2P, 256, 0, stream>>>(q, vc, kn);
  hist_kernel<<<4, 256, 0, stream>>>(labels, hist);

  dim3 grid(N2P / BN, N1 / BM);
  gemm_loss_kernel<<<grid, 256, 0, stream>>>(kn, labels, partials);

  finalize_kernel<<<4, 256, 0, stream>>>(partials, labels, hist, depth, out);
}

// Round 6
// 58.953 us; speedup vs baseline: 2.4111x; 1.1268x over previous
//
#include <hip/hip_runtime.h>
#include <math.h>

#define N1 1024
#define DPROJ 1024
#define M_NODES 4368
#define N2 (N1 + M_NODES)      // 5392
#define N2P 5504               // padded to 43*128 for the GEMM
#define L_LEAVES 4096
#define INV_T (1.0f / 0.07f)
#define NBX 43                 // N2P / BN

typedef __bf16 bf16;
typedef __bf16 bf16x4v __attribute__((ext_vector_type(4)));
typedef __bf16 bf16x8 __attribute__((ext_vector_type(8)));
typedef float f32x4 __attribute__((ext_vector_type(4)));

// ---------------------------------------------------------------------------
// Kernel A: fused normalize + bf16 cast. kn[row] = row/max(||row||,1e-12);
// rows >= N2 zero-filled (GEMM padding). Block 0 also zeroes d_out (stream
// order puts this before finalize's atomics; re-zeroed every call so graph
// replay stays deterministic).
// ---------------------------------------------------------------------------
__global__ __launch_bounds__(256) void normalize_kernel(
    const float* __restrict__ q, const float* __restrict__ vc,
    bf16* __restrict__ kn, float* __restrict__ out) {
  const int row = blockIdx.x;
  if (row == 0 && threadIdx.x == 0) { out[0] = 0.f; out[1] = 0.f; }
  bf16x4v* dst = (bf16x4v*)(kn + (size_t)row * DPROJ);
  if (row >= N2) {
    bf16x4v z = {(bf16)0.f, (bf16)0.f, (bf16)0.f, (bf16)0.f};
    dst[threadIdx.x] = z;
    return;
  }
  const float* src = (row < N1) ? q + (size_t)row * DPROJ
                                : vc + (size_t)(row - N1) * DPROJ;
  float4 v = ((const float4*)src)[threadIdx.x];
  float s = v.x * v.x + v.y * v.y + v.z * v.z + v.w * v.w;
  for (int off = 32; off > 0; off >>= 1) s += __shfl_down(s, off);
  __shared__ float wsum[4];
  const int lane = threadIdx.x & 63, wid = threadIdx.x >> 6;
  if (lane == 0) wsum[wid] = s;
  __syncthreads();
  const float tot = wsum[0] + wsum[1] + wsum[2] + wsum[3];
  const float inv = 1.0f / fmaxf(sqrtf(tot), 1e-12f);
  bf16x4v o = {(bf16)(v.x * inv), (bf16)(v.y * inv), (bf16)(v.z * inv),
               (bf16)(v.w * inv)};
  dst[threadIdx.x] = o;
}

// ---------------------------------------------------------------------------
// Kernel B: fused GEMM + loss partials. 64x128 tile, BK=32, 2x2 waves
// (wave tile 32x64), 688 blocks, ~4 blocks/CU.
// R6 change: 2-phase double-buffered pipeline (T3-minimum): issue next
// tile's global_load_lds FIRST, then ds_read+MFMA current tile, then ONE
// vmcnt(0)+barrier at iteration end — loads land under the compute phase.
// (R3's counted-vmcnt graft failed from grid starvation, not pipelining;
// R5 measured the serial loop at ~240 TF.)
// Epilogue: per-row analytic tree classification -> LDS reduce -> one plain
// store per (row, block-column); zero global atomics (R5 win).
// ---------------------------------------------------------------------------
#define BM 64
#define BN 128
#define BK 32
#define NT (DPROJ / BK)

__device__ __forceinline__ void gload16(const bf16* g, bf16* l) {
  __builtin_amdgcn_global_load_lds(
      (const __attribute__((address_space(1))) void*)g,
      (__attribute__((address_space(3))) void*)l, 16, 0, 0);
}

__global__ __launch_bounds__(256, 4) void gemm_loss_kernel(
    const bf16* __restrict__ kn, const int* __restrict__ labels,
    float* __restrict__ partials) {
  __shared__ bf16 As[2][BM][BK];         // 8 KB
  __shared__ bf16 Bs[2][BN][BK];         // 16 KB
  __shared__ int lab_s[N1];              // 4 KB
  __shared__ float blk_part[BM][2][6];   // 3 KB
  const int bx = blockIdx.x;
  const int j0 = bx * BN;
  const int i0 = blockIdx.y * BM;
  const int t = threadIdx.x;
  const int lane = t & 63, w = t >> 6;
  const int wm = w >> 1, wn = w & 1;   // wave grid 2x2, wave tile 32x64

  ((int4*)lab_s)[t] = ((const int4*)labels)[t];

  f32x4 acc[2][4] = {};

  // Staging: wave w stages A rows [16w,16w+16) and B rows {16w.., 16w+64..}.
  const int rik = lane >> 2;
  const int kk = (lane & 3) * 8;
  const bf16* gA = kn + (size_t)(i0 + w * 16 + rik) * DPROJ + kk;
  const bf16* gB0 = kn + (size_t)(j0 + w * 16 + rik) * DPROJ + kk;
  const bf16* gB1 = gB0 + (size_t)64 * DPROJ;

  const int ar = wm * 32 + (lane & 15);
  const int br = wn * 64 + (lane & 15);
  const int kf = (lane >> 4) * 8;

  // Prologue: stage tile 0 into buf 0; full drain covers lab_s too.
  gload16(gA, &As[0][w * 16][0]);
  gload16(gB0, &Bs[0][w * 16][0]);
  gload16(gB1, &Bs[0][w * 16 + 64][0]);
  __syncthreads();

#pragma unroll 2
  for (int it = 0; it < NT; ++it) {
    const int cur = it & 1;
    // Issue next tile's loads first — they complete under this tile's
    // compute + the end-of-iteration drain.
    if (it + 1 < NT) {
      const int k0n = (it + 1) * BK;
      gload16(gA + k0n, &As[cur ^ 1][w * 16][0]);
      gload16(gB0 + k0n, &Bs[cur ^ 1][w * 16][0]);
      gload16(gB1 + k0n, &Bs[cur ^ 1][w * 16 + 64][0]);
    }

    bf16x8 a[2], b[4];
#pragma unroll
    for (int m = 0; m < 2; ++m)
      a[m] = *(const bf16x8*)&As[cur][ar + m * 16][kf];
#pragma unroll
    for (int n = 0; n < 4; ++n)
      b[n] = *(const bf16x8*)&Bs[cur][br + n * 16][kf];
#pragma unroll
    for (int m = 0; m < 2; ++m)
#pragma unroll
      for (int n = 0; n < 4; ++n)
        acc[m][n] = __builtin_amdgcn_mfma_f32_16x16x32_bf16(
            a[m], b[n], acc[m][n], 0, 0, 0);

    // Single end-of-iteration sync: drains the 3 in-flight loads (they had
    // the whole compute phase to land) and fences this tile's ds_reads
    // before the next iteration overwrites the buffer.
    __syncthreads();
  }

  // Fused epilogue. C/D layout: col=lane&15, row=(lane>>4)*4+j [m89].
  const int g = lane >> 4;
  const int p = lane & 15;
#pragma unroll
  for (int m = 0; m < 2; ++m) {
#pragma unroll
    for (int j = 0; j < 4; ++j) {
      const int rloc = wm * 32 + m * 16 + g * 4 + j;
      const int gr = i0 + rloc;
      const int lab = lab_s[gr];
      const int a2 = lab >> 4, a1 = lab >> 8;
      float ps0 = 0, ps1 = 0, ps2 = 0, ns0 = 0, ns1 = 0, ns2 = 0;
#pragma unroll
      for (int n = 0; n < 4; ++n) {
        const int gc = j0 + wn * 64 + n * 16 + p;
        if (gc < N2) {
          const int nid = (gc < N1) ? lab_s[gc] : (gc - N1);
          const bool isLeaf = nid < L_LEAVES;
          const bool isD2 = (nid >= L_LEAVES) && (nid < L_LEAVES + 256);
          const bool eq = (nid == lab);
          const bool inS2 =
              (nid == L_LEAVES + a2) || (isLeaf && ((nid >> 4) == a2));
          const bool inS1 = (nid == L_LEAVES + 256 + a1) ||
                            (isD2 && (((nid - L_LEAVES) >> 4) == a1)) ||
                            (isLeaf && ((nid >> 8) == a1));
          const float v = acc[m][n][j] * INV_T;
          const float e = __expf(v);
          if (eq) ps2 += v; else ns2 += e;
          if (inS2) { if (!eq) ps1 += v; } else ns1 += e;
          if (inS1) { if (!inS2) ps0 += v; } else ns0 += e;
        }
      }
#pragma unroll
      for (int msk = 1; msk < 16; msk <<= 1) {
        ps0 += __shfl_xor(ps0, msk);
        ps1 += __shfl_xor(ps1, msk);
        ps2 += __shfl_xor(ps2, msk);
        ns0 += __shfl_xor(ns0, msk);
        ns1 += __shfl_xor(ns1, msk);
        ns2 += __shfl_xor(ns2, msk);
      }
      if (p == 0) {
        float* d = &blk_part[rloc][wn][0];
        d[0] = ps0; d[1] = ps1; d[2] = ps2;
        d[3] = ns0; d[4] = ns1; d[5] = ns2;
      }
    }
  }
  __syncthreads();
  for (int idx = t; idx < BM * 6; idx += 256) {
    const int r = idx / 6, k = idx % 6;
    const float val = blk_part[r][0][k] + blk_part[r][1][k];
    partials[((size_t)(i0 + r) * NBX + bx) * 6 + k] = val;
  }
}

// ---------------------------------------------------------------------------
// Kernel C: finalize. Builds the node-id label histogram in LDS (replaces
// the hist kernel + memset), sums the 43 per-block-column slices per row,
// then CE with analytic counts: |eq|=hist[lab]+1; |S2|=hist2+17;
// |S1|=hist1+273. Masked entries contribute exp(0)=1 -> +|set| in the LSE.
// ---------------------------------------------------------------------------
__global__ __launch_bounds__(256) void finalize_kernel(
    const float* __restrict__ partials, const int* __restrict__ labels,
    const float* __restrict__ depth, float* __restrict__ out) {
  __shared__ int hist_s[M_NODES];   // 17.4 KB
  const int t = threadIdx.x;
  for (int i = t; i < M_NODES; i += 256) hist_s[i] = 0;
  __syncthreads();
  for (int i = t; i < N1; i += 256) {
    const int lb = labels[i];
    atomicAdd(&hist_s[lb], 1);
    atomicAdd(&hist_s[L_LEAVES + (lb >> 4)], 1);
    atomicAdd(&hist_s[L_LEAVES + 256 + (lb >> 8)], 1);
  }
  __syncthreads();

  const int row = blockIdx.x * 256 + t;
  const int lab = labels[row];
  const int a2 = lab >> 4, a1 = lab >> 8;
  const int cEq = hist_s[lab] + 1;
  const int cS2 = hist_s[L_LEAVES + a2] + 17;
  const int cS1 = hist_s[L_LEAVES + 256 + a1] + 273;
  float ps0 = 0, ps1 = 0, ps2 = 0, ns0 = 0, ns1 = 0, ns2 = 0;
  const float* pp = partials + (size_t)row * NBX * 6;
  for (int b = 0; b < NBX; ++b) {
    ps0 += pp[b * 6 + 0];
    ps1 += pp[b * 6 + 1];
    ps2 += pp[b * 6 + 2];
    ns0 += pp[b * 6 + 3];
    ns1 += pp[b * 6 + 4];
    ns2 += pp[b * 6 + 5];
  }
  float ce = 0.f;
  {
    float pl = ps2 / fmaxf((float)cEq, 1e-6f);
    ce += logf(ns2 + (float)cEq + __expf(pl)) - pl;
  }
  {
    float pl = ps1 / fmaxf((float)(cS2 - cEq), 1e-6f);
    ce += logf(ns1 + (float)cS2 + __expf(pl)) - pl;
  }
  {
    float pl = ps0 / fmaxf((float)(cS1 - cS2), 1e-6f);
    ce += logf(ns0 + (float)cS1 + __expf(pl)) - pl;
  }
  float contrib = ce / depth[lab] * (3.0f / (float)N1);
  for (int off = 32; off > 0; off >>= 1) contrib += __shfl_down(contrib, off);
  __shared__ float wsum[4];
  const int lane = t & 63, wid = t >> 6;
  if (lane == 0) wsum[wid] = contrib;
  __syncthreads();
  if (t == 0) {
    const float tot = wsum[0] + wsum[1] + wsum[2] + wsum[3];
    atomicAdd(&out[0], tot);
    atomicAdd(&out[1], tot);
  }
}

// ---------------------------------------------------------------------------
extern "C" void kernel_launch(void* const* d_in, const int* in_sizes, int n_in,
                              void* d_out, int out_size, void* d_ws,
                              size_t ws_size, hipStream_t stream) {
  const float* q = (const float*)d_in[0];
  const float* vc = (const float*)d_in[1];
  const int* labels = (const int*)d_in[2];
  const float* depth = (const float*)d_in[6];
  float* out = (float*)d_out;

  bf16* kn = (bf16*)d_ws;  // N2P*DPROJ bf16 = 11.27 MB
  float* partials = (float*)((char*)d_ws + (size_t)N2P * DPROJ * sizeof(bf16));
  // partials: N1 * NBX * 6 floats (~1.06 MB), fully written -> no memset

  normalize_kernel<<<N2P, 256, 0, stream>>>(q, vc, kn, out);

  dim3 grid(N2P / BN, N1 / BM);
  gemm_loss_kernel<<<grid, 256, 0, stream>>>(kn, labels, partials);

  finalize_kernel<<<4, 256, 0, stream>>>(partials, labels, depth, out);
}

// Round 7
// 57.793 us; speedup vs baseline: 2.4595x; 1.0201x over previous
//
#include <hip/hip_runtime.h>
#include <math.h>

#define N1 1024
#define DPROJ 1024
#define M_NODES 4368
#define N2 (N1 + M_NODES)      // 5392
#define N2P 5504               // padded to 43*128 for the GEMM
#define L_LEAVES 4096
#define INV_T (1.0f / 0.07f)
#define NBX 43                 // N2P / BN

typedef __bf16 bf16;
typedef __bf16 bf16x4v __attribute__((ext_vector_type(4)));
typedef __bf16 bf16x8 __attribute__((ext_vector_type(8)));
typedef float f32x4 __attribute__((ext_vector_type(4)));

// ---------------------------------------------------------------------------
// Kernel A: fused normalize + bf16 cast. kn[row] = row/max(||row||,1e-12);
// rows >= N2 zero-filled (GEMM padding). Block 0 also zeroes d_out.
// ---------------------------------------------------------------------------
__global__ __launch_bounds__(256) void normalize_kernel(
    const float* __restrict__ q, const float* __restrict__ vc,
    bf16* __restrict__ kn, float* __restrict__ out) {
  const int row = blockIdx.x;
  if (row == 0 && threadIdx.x == 0) { out[0] = 0.f; out[1] = 0.f; }
  bf16x4v* dst = (bf16x4v*)(kn + (size_t)row * DPROJ);
  if (row >= N2) {
    bf16x4v z = {(bf16)0.f, (bf16)0.f, (bf16)0.f, (bf16)0.f};
    dst[threadIdx.x] = z;
    return;
  }
  const float* src = (row < N1) ? q + (size_t)row * DPROJ
                                : vc + (size_t)(row - N1) * DPROJ;
  float4 v = ((const float4*)src)[threadIdx.x];
  float s = v.x * v.x + v.y * v.y + v.z * v.z + v.w * v.w;
  for (int off = 32; off > 0; off >>= 1) s += __shfl_down(s, off);
  __shared__ float wsum[4];
  const int lane = threadIdx.x & 63, wid = threadIdx.x >> 6;
  if (lane == 0) wsum[wid] = s;
  __syncthreads();
  const float tot = wsum[0] + wsum[1] + wsum[2] + wsum[3];
  const float inv = 1.0f / fmaxf(sqrtf(tot), 1e-12f);
  bf16x4v o = {(bf16)(v.x * inv), (bf16)(v.y * inv), (bf16)(v.z * inv),
               (bf16)(v.w * inv)};
  dst[threadIdx.x] = o;
}

// ---------------------------------------------------------------------------
// Kernel B: fused GEMM + loss partials. Geometry/pipeline identical to R6
// (64x128 tile, BK=32, 2x2 waves of 32x64, 2-phase dbuf, 688 blocks).
// R7 change (ONLY): bank-conflict-free LDS via 2-row-period XOR swizzle.
// A 64B-row-stride [r][32] bf16 tile read as b128 is an 8-way conflict
// (bank quad repeats every 2 rows). slot = g ^ ((r>>1)&3) spreads a
// 16-row read-group across all 32 banks 2x (2-way = free, m136).
// global_load_lds writes linearly -> pre-swizzle the GLOBAL source slot
// with the same involution (stays inside one 64B segment: coalescing OK)
// and swizzle the ds_read slot (rule: both-sides-or-neither).
//   LDS[r][s] = global[r][s ^ ((r>>1)&3)]; read slot = g ^ ((r>>1)&3).
// ---------------------------------------------------------------------------
#define BM 64
#define BN 128
#define BK 32
#define NT (DPROJ / BK)

__device__ __forceinline__ void gload16(const bf16* g, bf16* l) {
  __builtin_amdgcn_global_load_lds(
      (const __attribute__((address_space(1))) void*)g,
      (__attribute__((address_space(3))) void*)l, 16, 0, 0);
}

__global__ __launch_bounds__(256, 4) void gemm_loss_kernel(
    const bf16* __restrict__ kn, const int* __restrict__ labels,
    float* __restrict__ partials) {
  __shared__ bf16 As[2][BM][BK];         // 8 KB
  __shared__ bf16 Bs[2][BN][BK];         // 16 KB
  __shared__ int lab_s[N1];              // 4 KB
  __shared__ float blk_part[BM][2][6];   // 3 KB
  const int bx = blockIdx.x;
  const int j0 = bx * BN;
  const int i0 = blockIdx.y * BM;
  const int t = threadIdx.x;
  const int lane = t & 63, w = t >> 6;
  const int wm = w >> 1, wn = w & 1;   // wave grid 2x2, wave tile 32x64

  ((int4*)lab_s)[t] = ((const int4*)labels)[t];

  f32x4 acc[2][4] = {};

  // Staging: wave w stages A rows [16w,16w+16) and B rows {16w.., 16w+64..}.
  // lane -> row = lane>>2, LDS 16B-slot = lane&3 (linear dest).
  // Global 16B-slot pre-swizzled: (lane&3) ^ ((row>>1)&3) = ^((lane>>3)&3).
  const int rik = lane >> 2;
  const int kswz = ((lane & 3) ^ ((lane >> 3) & 3)) * 8;
  const bf16* gA = kn + (size_t)(i0 + w * 16 + rik) * DPROJ + kswz;
  const bf16* gB0 = kn + (size_t)(j0 + w * 16 + rik) * DPROJ + kswz;
  const bf16* gB1 = gB0 + (size_t)64 * DPROJ;

  // Fragment reads: row = base + (lane&15) (bases are multiples of 16,
  // bank-neutral), logical k-slot g = lane>>4 -> LDS slot g ^ ((row>>1)&3).
  const int ar = wm * 32 + (lane & 15);
  const int br = wn * 64 + (lane & 15);
  const int kf = (((lane >> 4) ^ ((lane >> 1) & 3))) * 8;

  // Prologue: stage tile 0 into buf 0; full drain covers lab_s too.
  gload16(gA, &As[0][w * 16][0]);
  gload16(gB0, &Bs[0][w * 16][0]);
  gload16(gB1, &Bs[0][w * 16 + 64][0]);
  __syncthreads();

#pragma unroll 2
  for (int it = 0; it < NT; ++it) {
    const int cur = it & 1;
    // Issue next tile's loads first — they land under this tile's compute.
    if (it + 1 < NT) {
      const int k0n = (it + 1) * BK;
      gload16(gA + k0n, &As[cur ^ 1][w * 16][0]);
      gload16(gB0 + k0n, &Bs[cur ^ 1][w * 16][0]);
      gload16(gB1 + k0n, &Bs[cur ^ 1][w * 16 + 64][0]);
    }

    bf16x8 a[2], b[4];
#pragma unroll
    for (int m = 0; m < 2; ++m)
      a[m] = *(const bf16x8*)&As[cur][ar + m * 16][kf];
#pragma unroll
    for (int n = 0; n < 4; ++n)
      b[n] = *(const bf16x8*)&Bs[cur][br + n * 16][kf];
#pragma unroll
    for (int m = 0; m < 2; ++m)
#pragma unroll
      for (int n = 0; n < 4; ++n)
        acc[m][n] = __builtin_amdgcn_mfma_f32_16x16x32_bf16(
            a[m], b[n], acc[m][n], 0, 0, 0);

    __syncthreads();  // drains in-flight loads + fences ds_reads vs overwrite
  }

  // Fused epilogue. C/D layout: col=lane&15, row=(lane>>4)*4+j [m89].
  const int g = lane >> 4;
  const int p = lane & 15;
#pragma unroll
  for (int m = 0; m < 2; ++m) {
#pragma unroll
    for (int j = 0; j < 4; ++j) {
      const int rloc = wm * 32 + m * 16 + g * 4 + j;
      const int gr = i0 + rloc;
      const int lab = lab_s[gr];
      const int a2 = lab >> 4, a1 = lab >> 8;
      float ps0 = 0, ps1 = 0, ps2 = 0, ns0 = 0, ns1 = 0, ns2 = 0;
#pragma unroll
      for (int n = 0; n < 4; ++n) {
        const int gc = j0 + wn * 64 + n * 16 + p;
        if (gc < N2) {
          const int nid = (gc < N1) ? lab_s[gc] : (gc - N1);
          const bool isLeaf = nid < L_LEAVES;
          const bool isD2 = (nid >= L_LEAVES) && (nid < L_LEAVES + 256);
          const bool eq = (nid == lab);
          const bool inS2 =
              (nid == L_LEAVES + a2) || (isLeaf && ((nid >> 4) == a2));
          const bool inS1 = (nid == L_LEAVES + 256 + a1) ||
                            (isD2 && (((nid - L_LEAVES) >> 4) == a1)) ||
                            (isLeaf && ((nid >> 8) == a1));
          const float v = acc[m][n][j] * INV_T;
          const float e = __expf(v);
          if (eq) ps2 += v; else ns2 += e;
          if (inS2) { if (!eq) ps1 += v; } else ns1 += e;
          if (inS1) { if (!inS2) ps0 += v; } else ns0 += e;
        }
      }
#pragma unroll
      for (int msk = 1; msk < 16; msk <<= 1) {
        ps0 += __shfl_xor(ps0, msk);
        ps1 += __shfl_xor(ps1, msk);
        ps2 += __shfl_xor(ps2, msk);
        ns0 += __shfl_xor(ns0, msk);
        ns1 += __shfl_xor(ns1, msk);
        ns2 += __shfl_xor(ns2, msk);
      }
      if (p == 0) {
        float* d = &blk_part[rloc][wn][0];
        d[0] = ps0; d[1] = ps1; d[2] = ps2;
        d[3] = ns0; d[4] = ns1; d[5] = ns2;
      }
    }
  }
  __syncthreads();
  for (int idx = t; idx < BM * 6; idx += 256) {
    const int r = idx / 6, k = idx % 6;
    const float val = blk_part[r][0][k] + blk_part[r][1][k];
    partials[((size_t)(i0 + r) * NBX + bx) * 6 + k] = val;
  }
}

// ---------------------------------------------------------------------------
// Kernel C: finalize. LDS label histogram, sum 43 slices/row, CE with
// analytic counts: |eq|=hist[lab]+1; |S2|=hist2+17; |S1|=hist1+273.
// Masked entries contribute exp(0)=1 -> +|set| in the LSE.
// ---------------------------------------------------------------------------
__global__ __launch_bounds__(256) void finalize_kernel(
    const float* __restrict__ partials, const int* __restrict__ labels,
    const float* __restrict__ depth, float* __restrict__ out) {
  __shared__ int hist_s[M_NODES];   // 17.4 KB
  const int t = threadIdx.x;
  for (int i = t; i < M_NODES; i += 256) hist_s[i] = 0;
  __syncthreads();
  for (int i = t; i < N1; i += 256) {
    const int lb = labels[i];
    atomicAdd(&hist_s[lb], 1);
    atomicAdd(&hist_s[L_LEAVES + (lb >> 4)], 1);
    atomicAdd(&hist_s[L_LEAVES + 256 + (lb >> 8)], 1);
  }
  __syncthreads();

  const int row = blockIdx.x * 256 + t;
  const int lab = labels[row];
  const int a2 = lab >> 4, a1 = lab >> 8;
  const int cEq = hist_s[lab] + 1;
  const int cS2 = hist_s[L_LEAVES + a2] + 17;
  const int cS1 = hist_s[L_LEAVES + 256 + a1] + 273;
  float ps0 = 0, ps1 = 0, ps2 = 0, ns0 = 0, ns1 = 0, ns2 = 0;
  const float* pp = partials + (size_t)row * NBX * 6;
  for (int b = 0; b < NBX; ++b) {
    ps0 += pp[b * 6 + 0];
    ps1 += pp[b * 6 + 1];
    ps2 += pp[b * 6 + 2];
    ns0 += pp[b * 6 + 3];
    ns1 += pp[b * 6 + 4];
    ns2 += pp[b * 6 + 5];
  }
  float ce = 0.f;
  {
    float pl = ps2 / fmaxf((float)cEq, 1e-6f);
    ce += logf(ns2 + (float)cEq + __expf(pl)) - pl;
  }
  {
    float pl = ps1 / fmaxf((float)(cS2 - cEq), 1e-6f);
    ce += logf(ns1 + (float)cS2 + __expf(pl)) - pl;
  }
  {
    float pl = ps0 / fmaxf((float)(cS1 - cS2), 1e-6f);
    ce += logf(ns0 + (float)cS1 + __expf(pl)) - pl;
  }
  float contrib = ce / depth[lab] * (3.0f / (float)N1);
  for (int off = 32; off > 0; off >>= 1) contrib += __shfl_down(contrib, off);
  __shared__ float wsum[4];
  const int lane = t & 63, wid = t >> 6;
  if (lane == 0) wsum[wid] = contrib;
  __syncthreads();
  if (t == 0) {
    const float tot = wsum[0] + wsum[1] + wsum[2] + wsum[3];
    atomicAdd(&out[0], tot);
    atomicAdd(&out[1], tot);
  }
}

// ---------------------------------------------------------------------------
extern "C" void kernel_launch(void* const* d_in, const int* in_sizes, int n_in,
                              void* d_out, int out_size, void* d_ws,
                              size_t ws_size, hipStream_t stream) {
  const float* q = (const float*)d_in[0];
  const float* vc = (const float*)d_in[1];
  const int* labels = (const int*)d_in[2];
  const float* depth = (const float*)d_in[6];
  float* out = (float*)d_out;

  bf16* kn = (bf16*)d_ws;  // N2P*DPROJ bf16 = 11.27 MB
  float* partials = (float*)((char*)d_ws + (size_t)N2P * DPROJ * sizeof(bf16));
  // partials: N1 * NBX * 6 floats (~1.06 MB), fully written -> no memset

  normalize_kernel<<<N2P, 256, 0, stream>>>(q, vc, kn, out);

  dim3 grid(N2P / BN, N1 / BM);
  gemm_loss_kernel<<<grid, 256, 0, stream>>>(kn, labels, partials);

  finalize_kernel<<<4, 256, 0, stream>>>(partials, labels, depth, out);
}

// Round 8
// 55.009 us; speedup vs baseline: 2.5840x; 1.0506x over previous
//
#include <hip/hip_runtime.h>
#include <math.h>

#define N1 1024
#define DPROJ 1024
#define M_NODES 4368
#define N2 (N1 + M_NODES)      // 5392
#define N2P 5504               // padded to 43*128 for the GEMM
#define L_LEAVES 4096
#define INV_T (1.0f / 0.07f)
#define NBX 43                 // N2P / BN

typedef __bf16 bf16;
typedef __bf16 bf16x4v __attribute__((ext_vector_type(4)));
typedef __bf16 bf16x8 __attribute__((ext_vector_type(8)));
typedef float f32x4 __attribute__((ext_vector_type(4)));

// ---------------------------------------------------------------------------
// Kernel A: fused normalize + bf16 cast. kn[row] = row/max(||row||,1e-12);
// rows >= N2 zero-filled (GEMM padding). Block 0 also zeroes d_out.
// ---------------------------------------------------------------------------
__global__ __launch_bounds__(256) void normalize_kernel(
    const float* __restrict__ q, const float* __restrict__ vc,
    bf16* __restrict__ kn, float* __restrict__ out) {
  const int row = blockIdx.x;
  if (row == 0 && threadIdx.x == 0) { out[0] = 0.f; out[1] = 0.f; }
  bf16x4v* dst = (bf16x4v*)(kn + (size_t)row * DPROJ);
  if (row >= N2) {
    bf16x4v z = {(bf16)0.f, (bf16)0.f, (bf16)0.f, (bf16)0.f};
    dst[threadIdx.x] = z;
    return;
  }
  const float* src = (row < N1) ? q + (size_t)row * DPROJ
                                : vc + (size_t)(row - N1) * DPROJ;
  float4 v = ((const float4*)src)[threadIdx.x];
  float s = v.x * v.x + v.y * v.y + v.z * v.z + v.w * v.w;
  for (int off = 32; off > 0; off >>= 1) s += __shfl_down(s, off);
  __shared__ float wsum[4];
  const int lane = threadIdx.x & 63, wid = threadIdx.x >> 6;
  if (lane == 0) wsum[wid] = s;
  __syncthreads();
  const float tot = wsum[0] + wsum[1] + wsum[2] + wsum[3];
  const float inv = 1.0f / fmaxf(sqrtf(tot), 1e-12f);
  bf16x4v o = {(bf16)(v.x * inv), (bf16)(v.y * inv), (bf16)(v.z * inv),
               (bf16)(v.w * inv)};
  dst[threadIdx.x] = o;
}

// ---------------------------------------------------------------------------
// Kernel B: fused GEMM + loss partials. Geometry identical to R7 (64x128
// tile, BK=32, 2x2 waves of 32x64, 688 blocks, XOR-swizzled LDS).
// R8 change (ONLY): sync structure. R7's __syncthreads() drains vmcnt(0)
// every iteration -> the 3 prefetch loads must land inside the ~150-cyc
// compute phase; ~300-500 cyc of latency exposed per iter (measured
// ~1000 cyc/iter vs ~150 compute). Now: 3 LDS buffers, 2-tiles-ahead
// prefetch, counted s_waitcnt vmcnt(6) (per-wave: its own oldest 3 = the
// current tile; wait+barrier => all waves' tiles complete) and raw
// s_barriers with NO drain — in-flight loads get ~2 iterations of slack
// (T3/T4; R3's failure was grid starvation + sched_barrier pinning, both
// absent here).
// ---------------------------------------------------------------------------
#define BM 64
#define BN 128
#define BK 32
#define NT (DPROJ / BK)

__device__ __forceinline__ void gload16(const bf16* g, bf16* l) {
  __builtin_amdgcn_global_load_lds(
      (const __attribute__((address_space(1))) void*)g,
      (__attribute__((address_space(3))) void*)l, 16, 0, 0);
}

__global__ __launch_bounds__(256, 3) void gemm_loss_kernel(
    const bf16* __restrict__ kn, const int* __restrict__ labels,
    float* __restrict__ partials) {
  __shared__ bf16 As[3][BM][BK];         // 12 KB
  __shared__ bf16 Bs[3][BN][BK];         // 24 KB
  __shared__ int lab_s[N1];              // 4 KB
  __shared__ float blk_part[BM][2][6];   // 3 KB
  const int bx = blockIdx.x;
  const int j0 = bx * BN;
  const int i0 = blockIdx.y * BM;
  const int t = threadIdx.x;
  const int lane = t & 63, w = t >> 6;
  const int wm = w >> 1, wn = w & 1;   // wave grid 2x2, wave tile 32x64

  ((int4*)lab_s)[t] = ((const int4*)labels)[t];

  f32x4 acc[2][4] = {};

  // Staging: wave w stages A rows [16w,16w+16) and B rows {16w.., 16w+64..}.
  // lane -> row = lane>>2, LDS 16B-slot = lane&3 (linear dest).
  // Global 16B-slot pre-swizzled: (lane&3) ^ ((row>>1)&3) = ^((lane>>3)&3).
  const int rik = lane >> 2;
  const int kswz = ((lane & 3) ^ ((lane >> 3) & 3)) * 8;
  const bf16* gA = kn + (size_t)(i0 + w * 16 + rik) * DPROJ + kswz;
  const bf16* gB0 = kn + (size_t)(j0 + w * 16 + rik) * DPROJ + kswz;
  const bf16* gB1 = gB0 + (size_t)64 * DPROJ;

  // Fragment reads: row = base + (lane&15), logical k-slot g = lane>>4 ->
  // LDS slot g ^ ((row>>1)&3). Conflict-free (R7).
  const int ar = wm * 32 + (lane & 15);
  const int br = wn * 64 + (lane & 15);
  const int kf = (((lane >> 4) ^ ((lane >> 1) & 3))) * 8;

  // Prologue: stage tiles 0,1 into bufs 0,1. __syncthreads drains all
  // (also makes lab_s visible) — the only full drain in the kernel.
  gload16(gA, &As[0][w * 16][0]);
  gload16(gB0, &Bs[0][w * 16][0]);
  gload16(gB1, &Bs[0][w * 16 + 64][0]);
  gload16(gA + BK, &As[1][w * 16][0]);
  gload16(gB0 + BK, &Bs[1][w * 16][0]);
  gload16(gB1 + BK, &Bs[1][w * 16 + 64][0]);
  __syncthreads();

#pragma unroll 3
  for (int it = 0; it < NT; ++it) {
    const int cur = it % 3;
    // Issue tile it+2 into buf (it+2)%3. That buffer was last READ at
    // iter it-1; the end-of-iter barrier below guarantees all waves
    // finished those reads before any wave issues these writes.
    if (it + 2 < NT) {
      const int k0n = (it + 2) * BK;
      const int nb = (it + 2) % 3;
      gload16(gA + k0n, &As[nb][w * 16][0]);
      gload16(gB0 + k0n, &Bs[nb][w * 16][0]);
      gload16(gB1 + k0n, &Bs[nb][w * 16 + 64][0]);
      asm volatile("s_waitcnt vmcnt(6)" ::: "memory");   // oldest 3 = tile it
    } else if (it + 1 < NT) {
      asm volatile("s_waitcnt vmcnt(3)" ::: "memory");
    } else {
      asm volatile("s_waitcnt vmcnt(0)" ::: "memory");
    }
    __builtin_amdgcn_s_barrier();   // all waves' tile-it loads complete

    bf16x8 a[2], b[4];
#pragma unroll
    for (int m = 0; m < 2; ++m)
      a[m] = *(const bf16x8*)&As[cur][ar + m * 16][kf];
#pragma unroll
    for (int n = 0; n < 4; ++n)
      b[n] = *(const bf16x8*)&Bs[cur][br + n * 16][kf];
#pragma unroll
    for (int m = 0; m < 2; ++m)
#pragma unroll
      for (int n = 0; n < 4; ++n)
        acc[m][n] = __builtin_amdgcn_mfma_f32_16x16x32_bf16(
            a[m], b[n], acc[m][n], 0, 0, 0);

    __builtin_amdgcn_s_barrier();   // reads of buf[cur] done -> reusable
  }

  // Fused epilogue. C/D layout: col=lane&15, row=(lane>>4)*4+j [m89].
  const int g = lane >> 4;
  const int p = lane & 15;
#pragma unroll
  for (int m = 0; m < 2; ++m) {
#pragma unroll
    for (int j = 0; j < 4; ++j) {
      const int rloc = wm * 32 + m * 16 + g * 4 + j;
      const int gr = i0 + rloc;
      const int lab = lab_s[gr];
      const int a2 = lab >> 4, a1 = lab >> 8;
      float ps0 = 0, ps1 = 0, ps2 = 0, ns0 = 0, ns1 = 0, ns2 = 0;
#pragma unroll
      for (int n = 0; n < 4; ++n) {
        const int gc = j0 + wn * 64 + n * 16 + p;
        if (gc < N2) {
          const int nid = (gc < N1) ? lab_s[gc] : (gc - N1);
          const bool isLeaf = nid < L_LEAVES;
          const bool isD2 = (nid >= L_LEAVES) && (nid < L_LEAVES + 256);
          const bool eq = (nid == lab);
          const bool inS2 =
              (nid == L_LEAVES + a2) || (isLeaf && ((nid >> 4) == a2));
          const bool inS1 = (nid == L_LEAVES + 256 + a1) ||
                            (isD2 && (((nid - L_LEAVES) >> 4) == a1)) ||
                            (isLeaf && ((nid >> 8) == a1));
          const float v = acc[m][n][j] * INV_T;
          const float e = __expf(v);
          if (eq) ps2 += v; else ns2 += e;
          if (inS2) { if (!eq) ps1 += v; } else ns1 += e;
          if (inS1) { if (!inS2) ps0 += v; } else ns0 += e;
        }
      }
#pragma unroll
      for (int msk = 1; msk < 16; msk <<= 1) {
        ps0 += __shfl_xor(ps0, msk);
        ps1 += __shfl_xor(ps1, msk);
        ps2 += __shfl_xor(ps2, msk);
        ns0 += __shfl_xor(ns0, msk);
        ns1 += __shfl_xor(ns1, msk);
        ns2 += __shfl_xor(ns2, msk);
      }
      if (p == 0) {
        float* d = &blk_part[rloc][wn][0];
        d[0] = ps0; d[1] = ps1; d[2] = ps2;
        d[3] = ns0; d[4] = ns1; d[5] = ns2;
      }
    }
  }
  __syncthreads();
  for (int idx = t; idx < BM * 6; idx += 256) {
    const int r = idx / 6, k = idx % 6;
    const float val = blk_part[r][0][k] + blk_part[r][1][k];
    partials[((size_t)(i0 + r) * NBX + bx) * 6 + k] = val;
  }
}

// ---------------------------------------------------------------------------
// Kernel C: finalize. LDS label histogram, sum 43 slices/row, CE with
// analytic counts: |eq|=hist[lab]+1; |S2|=hist2+17; |S1|=hist1+273.
// Masked entries contribute exp(0)=1 -> +|set| in the LSE.
// ---------------------------------------------------------------------------
__global__ __launch_bounds__(256) void finalize_kernel(
    const float* __restrict__ partials, const int* __restrict__ labels,
    const float* __restrict__ depth, float* __restrict__ out) {
  __shared__ int hist_s[M_NODES];   // 17.4 KB
  const int t = threadIdx.x;
  for (int i = t; i < M_NODES; i += 256) hist_s[i] = 0;
  __syncthreads();
  for (int i = t; i < N1; i += 256) {
    const int lb = labels[i];
    atomicAdd(&hist_s[lb], 1);
    atomicAdd(&hist_s[L_LEAVES + (lb >> 4)], 1);
    atomicAdd(&hist_s[L_LEAVES + 256 + (lb >> 8)], 1);
  }
  __syncthreads();

  const int row = blockIdx.x * 256 + t;
  const int lab = labels[row];
  const int a2 = lab >> 4, a1 = lab >> 8;
  const int cEq = hist_s[lab] + 1;
  const int cS2 = hist_s[L_LEAVES + a2] + 17;
  const int cS1 = hist_s[L_LEAVES + 256 + a1] + 273;
  float ps0 = 0, ps1 = 0, ps2 = 0, ns0 = 0, ns1 = 0, ns2 = 0;
  const float* pp = partials + (size_t)row * NBX * 6;
  for (int b = 0; b < NBX; ++b) {
    ps0 += pp[b * 6 + 0];
    ps1 += pp[b * 6 + 1];
    ps2 += pp[b * 6 + 2];
    ns0 += pp[b * 6 + 3];
    ns1 += pp[b * 6 + 4];
    ns2 += pp[b * 6 + 5];
  }
  float ce = 0.f;
  {
    float pl = ps2 / fmaxf((float)cEq, 1e-6f);
    ce += logf(ns2 + (float)cEq + __expf(pl)) - pl;
  }
  {
    float pl = ps1 / fmaxf((float)(cS2 - cEq), 1e-6f);
    ce += logf(ns1 + (float)cS2 + __expf(pl)) - pl;
  }
  {
    float pl = ps0 / fmaxf((float)(cS1 - cS2), 1e-6f);
    ce += logf(ns0 + (float)cS1 + __expf(pl)) - pl;
  }
  float contrib = ce / depth[lab] * (3.0f / (float)N1);
  for (int off = 32; off > 0; off >>= 1) contrib += __shfl_down(contrib, off);
  __shared__ float wsum[4];
  const int lane = t & 63, wid = t >> 6;
  if (lane == 0) wsum[wid] = contrib;
  __syncthreads();
  if (t == 0) {
    const float tot = wsum[0] + wsum[1] + wsum[2] + wsum[3];
    atomicAdd(&out[0], tot);
    atomicAdd(&out[1], tot);
  }
}

// ---------------------------------------------------------------------------
extern "C" void kernel_launch(void* const* d_in, const int* in_sizes, int n_in,
                              void* d_out, int out_size, void* d_ws,
                              size_t ws_size, hipStream_t stream) {
  const float* q = (const float*)d_in[0];
  const float* vc = (const float*)d_in[1];
  const int* labels = (const int*)d_in[2];
  const float* depth = (const float*)d_in[6];
  float* out = (float*)d_out;

  bf16* kn = (bf16*)d_ws;  // N2P*DPROJ bf16 = 11.27 MB
  float* partials = (float*)((char*)d_ws + (size_t)N2P * DPROJ * sizeof(bf16));
  // partials: N1 * NBX * 6 floats (~1.06 MB), fully written -> no memset

  normalize_kernel<<<N2P, 256, 0, stream>>>(q, vc, kn, out);

  dim3 grid(N2P / BN, N1 / BM);
  gemm_loss_kernel<<<grid, 256, 0, stream>>>(kn, labels, partials);

  finalize_kernel<<<4, 256, 0, stream>>>(partials, labels, depth, out);
}